// Round 6
// baseline (478.580 us; speedup 1.0000x reference)
//
#include <hip/hip_runtime.h>

// GAT as flash-attention, round 6: LDS-bandwidth-optimized phase 2.
//  - 32 i-rows/wave (2 Q-frags, 8 O-accs): halves LDS read traffic per row
//  - XOR-swizzled stride-64 LDS tiles: conflict-free K(b128)/V(b64) reads
//  - 8-way j-split (512 j/block) keeps 1024 blocks -> 16 waves/CU
//  - prefetch issued after the barrier (barrier vmcnt(0) drains nothing)
//  - sN staged to LDS once (off the vmcnt path)
//  - mask kernel streams adj once at HBM roofline into 64-bit bitmasks

typedef __attribute__((ext_vector_type(4))) float f32x4;
typedef __attribute__((ext_vector_type(4))) _Float16 h16x4;
typedef __attribute__((ext_vector_type(8))) _Float16 h16x8;
typedef __attribute__((ext_vector_type(2))) __fp16 fp16x2;

#define L2E 1.4426950408889634f

// ---------------- phase 0: adj -> bitmask (pure HBM stream) ----------------
__global__ __launch_bounds__(256) void gat_mask(
    const int* __restrict__ adj,                 // [4][4096][4096]
    unsigned long long* __restrict__ mask)       // [4][4096][64]
{
  const int tid = threadIdx.x;
  const int w = tid >> 6, lane = tid & 63;
  const size_t row = (size_t)blockIdx.x * 4 + w;
  const int* ap = adj + row * 4096 + lane;
  unsigned long long* mp = mask + row * 64;
#pragma unroll 4
  for (int s = 0; s < 64; ++s) {
    int v = ap[s * 64];
    unsigned long long m = __ballot(v > 0);
    if (lane == 0) mp[s] = m;
  }
}

// ---------------- phase 1: h = x@W (fp32), scaled biases, fp16 packs --------
__global__ __launch_bounds__(256) void gat_phase1(
    const float* __restrict__ x,        // [4][4096][128]
    const float* __restrict__ W,        // [128][64]
    const float* __restrict__ a,        // [192]
    _Float16* __restrict__ h16,         // [4][4096][64]
    _Float16* __restrict__ hT16,        // [4][64][4096]
    _Float16* __restrict__ q16,         // [4][4096][64]  (pre-scaled by log2e)
    float* __restrict__ sS,             // [4][4096]      (pre-scaled by log2e)
    float* __restrict__ sN)             // [4][4096]      (pre-scaled by log2e)
{
  __shared__ float xs[32 * 132];        // x tile [row][k], stride 132
  __shared__ float ws[128 * 64];        // W natural [k][f] (broadcast/2-way)
  const int tid = threadIdx.x;
  const int bx  = blockIdx.x;
  const int b   = bx >> 7;
  const int n0  = (bx & 127) << 5;
  const float* xb = x + ((size_t)b * 4096 + n0) * 128;

#pragma unroll
  for (int p = 0; p < 4; ++p) {
    int idx = tid + p * 256;
    int row = idx >> 5, c4 = idx & 31;
    float4 v = ((const float4*)(xb + row * 128))[c4];
    *(float4*)&xs[row * 132 + c4 * 4] = v;
  }
#pragma unroll
  for (int p = 0; p < 8; ++p) {
    int idx = tid + p * 256;
    ((float4*)ws)[idx] = ((const float4*)W)[idx];
  }
  __syncthreads();

  const int tx = tid & 15;   // f = 4*tx + fi
  const int ty = tid >> 4;   // n = n0 + 2*ty + ri
  f32x4 acc0 = (f32x4){0.f, 0.f, 0.f, 0.f};
  f32x4 acc1 = (f32x4){0.f, 0.f, 0.f, 0.f};

#pragma unroll 8
  for (int k = 0; k < 128; k += 4) {
    f32x4 x0 = *(const f32x4*)&xs[(2 * ty) * 132 + k];
    f32x4 x1 = *(const f32x4*)&xs[(2 * ty + 1) * 132 + k];
    f32x4 w0 = *(const f32x4*)&ws[(k + 0) * 64 + 4 * tx];
    f32x4 w1 = *(const f32x4*)&ws[(k + 1) * 64 + 4 * tx];
    f32x4 w2 = *(const f32x4*)&ws[(k + 2) * 64 + 4 * tx];
    f32x4 w3 = *(const f32x4*)&ws[(k + 3) * 64 + 4 * tx];
    acc0 += x0.x * w0 + x0.y * w1 + x0.z * w2 + x0.w * w3;
    acc1 += x1.x * w0 + x1.y * w1 + x1.z * w2 + x1.w * w3;
  }
  float acc[2][4] = {{acc0.x, acc0.y, acc0.z, acc0.w},
                     {acc1.x, acc1.y, acc1.z, acc1.w}};

  float a1r[4], a2r[4], a3r[4];
#pragma unroll
  for (int f = 0; f < 4; ++f) {
    a1r[f] = a[4 * tx + f] * L2E;
    a2r[f] = a[64 + 4 * tx + f] * L2E;
    a3r[f] = a[128 + 4 * tx + f] * L2E;
  }
  const size_t bN = (size_t)b * 4096;
#pragma unroll
  for (int r = 0; r < 2; ++r) {
    float p1 = 0.f, p2 = 0.f;
#pragma unroll
    for (int f = 0; f < 4; ++f) { p1 += acc[r][f] * a1r[f]; p2 += acc[r][f] * a2r[f]; }
#pragma unroll
    for (int m = 1; m < 16; m <<= 1) {
      p1 += __shfl_xor(p1, m, 64);
      p2 += __shfl_xor(p2, m, 64);
    }
    if (tx == 0) {
      int n = n0 + 2 * ty + r;
      sS[bN + n] = p1;
      sN[bN + n] = p2;
    }
  }
#pragma unroll
  for (int r = 0; r < 2; ++r) {
    int n = n0 + 2 * ty + r;
    h16x4 hv, qv;
#pragma unroll
    for (int f = 0; f < 4; ++f) {
      hv[f] = (_Float16)acc[r][f];
      qv[f] = (_Float16)(acc[r][f] * a3r[f]);
    }
    *(h16x4*)&h16[(bN + n) * 64 + 4 * tx] = hv;
    *(h16x4*)&q16[(bN + n) * 64 + 4 * tx] = qv;
  }
  __syncthreads();                       // xs reads done; reuse as hT staging
  _Float16* hTs = (_Float16*)xs;         // [64][40] halves
#pragma unroll
  for (int f = 0; f < 4; ++f)
#pragma unroll
    for (int r = 0; r < 2; ++r)
      hTs[(4 * tx + f) * 40 + 2 * ty + r] = (_Float16)acc[r][f];
  __syncthreads();
  {
    int f = tid >> 2, part = tid & 3;
    uint4 v = *(uint4*)&hTs[f * 40 + 8 * part];
    *(uint4*)&hT16[((size_t)b * 64 + f) * 4096 + n0 + 8 * part] = v;
  }
}

// ---------------- phase 2: masked softmax-attention partials ----------------
// 1024 blocks (b, split(8), itile(32)) x 256 thr; wave = 32 i-rows; 512-j
// quarter = 8 tiles of 64. XOR-swizzled LDS, 1 barrier/tile.
// MFMA layouts: 16x16x32 A[m=lane&15][k=qd*8+j], B[k=qd*8+j][n=lane&15],
//               16x16x16 A[m=lane&15][k=qd*4+r], B[k=qd*4+r][n=lane&15],
//               C/D row=4*qd+reg, col=lane&15.
__global__ __launch_bounds__(256, 4) void gat_phase2(
    const _Float16* __restrict__ h16,
    const _Float16* __restrict__ hT16,
    const _Float16* __restrict__ q16,
    const float* __restrict__ sS,
    const float* __restrict__ sN,
    const unsigned long long* __restrict__ mask,  // [4][4096][64]
    float* __restrict__ Opart,          // [8][16384][64]
    float* __restrict__ lpart)          // [8][16384]
{
  __shared__ _Float16 Kb[2][4096];   // K tile [j][f], stride 64, 16B-chunk^(j&7)
  __shared__ _Float16 Tb[2][4096];   // V^T tile [f][j], stride 64, 8B-chunk^(f&15)
  __shared__ float sNl[512];

  const int tid = threadIdx.x;
  const int w = tid >> 6, lane = tid & 63;
  const int qd = lane >> 4, c = lane & 15;
  const int bx = blockIdx.x;
  const int b = bx & 3;
  const int split = (bx >> 2) & 7;
  const int it = bx >> 5;
  const int i0 = it * 128 + w * 32;
  const int jq0 = split * 512;
  const size_t bN = (size_t)b * 4096;

  // Q fragments (B-op of S^T) for both 16-row halves
  const _Float16* qA = q16 + (bN + i0 + c) * 64;
  const _Float16* qB = q16 + (bN + i0 + 16 + c) * 64;
  h16x8 QA0 = *(const h16x8*)(qA + qd * 8);
  h16x8 QA1 = *(const h16x8*)(qA + 32 + qd * 8);
  h16x8 QB0 = *(const h16x8*)(qB + qd * 8);
  h16x8 QB1 = *(const h16x8*)(qB + 32 + qd * 8);
  const float ssA = sS[bN + i0 + c];
  const float ssB = sS[bN + i0 + 16 + c];

  const unsigned long long* mpA = mask + (bN + i0 + c) * 64 + (jq0 >> 6);
  const unsigned long long* mpB = mask + (bN + i0 + 16 + c) * 64 + (jq0 >> 6);

  // staging addressing: thread -> row srow(+32), 16B chunk
  const int srow = tid >> 3, chunk = tid & 7;
  const int ksw = (chunk ^ (srow & 7)) << 3;          // K swizzled half-offset
  const int tsw = (chunk ^ ((srow >> 1) & 7)) << 3;   // T swizzled half-offset
  const bool tswap = (srow & 1);
  const _Float16* hsrc = h16 + (bN + jq0 + srow) * 64 + chunk * 8;
  const _Float16* tsrc = hT16 + ((size_t)b * 64 + srow) * 4096 + jq0 + chunk * 8;

  f32x4 OA[4], OB[4];
#pragma unroll
  for (int ft = 0; ft < 4; ++ft) {
    OA[ft] = (f32x4){0.f, 0.f, 0.f, 0.f};
    OB[ft] = (f32x4){0.f, 0.f, 0.f, 0.f};
  }
  float lsumA = 0.f, lsumB = 0.f;

  // stage tile 0 into buffer 0 + sN into LDS + first masks
  {
    uint4 k0 = *(const uint4*)hsrc, k1 = *(const uint4*)(hsrc + 32 * 64);
    uint4 t0 = *(const uint4*)tsrc, t1 = *(const uint4*)(tsrc + 32 * 4096);
    *(uint4*)&Kb[0][srow * 64 + ksw] = k0;
    *(uint4*)&Kb[0][(srow + 32) * 64 + ksw] = k1;
    uint4 s0 = tswap ? (uint4){t0.z, t0.w, t0.x, t0.y} : t0;
    uint4 s1 = tswap ? (uint4){t1.z, t1.w, t1.x, t1.y} : t1;
    *(uint4*)&Tb[0][srow * 64 + tsw] = s0;
    *(uint4*)&Tb[0][(srow + 32) * 64 + tsw] = s1;
  }
  if (tid < 128) ((f32x4*)sNl)[tid] = *(const f32x4*)(sN + bN + jq0 + tid * 4);
  unsigned long long mA = mpA[0], mB = mpB[0];

  for (int t = 0; t < 8; ++t) {
    __syncthreads();                                // buf[t&1] (+sN) visible

    uint4 kr0, kr1, tr0, tr1;
    unsigned long long mAn = mA, mBn = mB;
    if (t < 7) {                                    // prefetch AFTER barrier
      const _Float16* hs = hsrc + (t + 1) * 4096;
      const _Float16* ts = tsrc + (t + 1) * 64;
      kr0 = *(const uint4*)hs; kr1 = *(const uint4*)(hs + 32 * 64);
      tr0 = *(const uint4*)ts; tr1 = *(const uint4*)(ts + 32 * 4096);
      mAn = mpA[t + 1]; mBn = mpB[t + 1];
    }

    const _Float16* Kc = &Kb[t & 1][0];
    const _Float16* Tc = &Tb[t & 1][0];
#pragma unroll
    for (int ct = 0; ct < 4; ++ct) {
      const int krow = 16 * ct + c;
      h16x8 Kf0 = *(const h16x8*)&Kc[krow * 64 + ((qd ^ (c & 7)) << 3)];
      h16x8 Kf1 = *(const h16x8*)&Kc[krow * 64 + (((qd + 4) ^ (c & 7)) << 3)];
      f32x4 SvA = (f32x4){0.f, 0.f, 0.f, 0.f};
      SvA = __builtin_amdgcn_mfma_f32_16x16x32_f16(Kf0, QA0, SvA, 0, 0, 0);
      SvA = __builtin_amdgcn_mfma_f32_16x16x32_f16(Kf1, QA1, SvA, 0, 0, 0);
      f32x4 SvB = (f32x4){0.f, 0.f, 0.f, 0.f};
      SvB = __builtin_amdgcn_mfma_f32_16x16x32_f16(Kf0, QB0, SvB, 0, 0, 0);
      SvB = __builtin_amdgcn_mfma_f32_16x16x32_f16(Kf1, QB1, SvB, 0, 0, 0);

      f32x4 snv = ((const f32x4*)sNl)[t * 16 + 4 * ct + qd];
      const int sh = 16 * ct + 4 * qd;

      f32x4 evA = SvA + snv + ssA;
      f32x4 tvA = __builtin_elementwise_max(evA, evA * 0.2f);
      unsigned bA = (unsigned)(mA >> sh);
      float a0 = __builtin_amdgcn_exp2f(tvA.x);
      float a1 = __builtin_amdgcn_exp2f(tvA.y);
      float a2 = __builtin_amdgcn_exp2f(tvA.z);
      float a3 = __builtin_amdgcn_exp2f(tvA.w);
      a0 = (bA & 1u) ? a0 : 0.f;
      a1 = (bA & 2u) ? a1 : 0.f;
      a2 = (bA & 4u) ? a2 : 0.f;
      a3 = (bA & 8u) ? a3 : 0.f;
      lsumA += (a0 + a1) + (a2 + a3);
      fp16x2 al = __builtin_amdgcn_cvt_pkrtz(a0, a1);
      fp16x2 ah = __builtin_amdgcn_cvt_pkrtz(a2, a3);
      h16x4 PfA = (h16x4){(_Float16)al.x, (_Float16)al.y,
                          (_Float16)ah.x, (_Float16)ah.y};

      f32x4 evB = SvB + snv + ssB;
      f32x4 tvB = __builtin_elementwise_max(evB, evB * 0.2f);
      unsigned bB = (unsigned)(mB >> sh);
      float b0 = __builtin_amdgcn_exp2f(tvB.x);
      float b1 = __builtin_amdgcn_exp2f(tvB.y);
      float b2 = __builtin_amdgcn_exp2f(tvB.z);
      float b3 = __builtin_amdgcn_exp2f(tvB.w);
      b0 = (bB & 1u) ? b0 : 0.f;
      b1 = (bB & 2u) ? b1 : 0.f;
      b2 = (bB & 4u) ? b2 : 0.f;
      b3 = (bB & 8u) ? b3 : 0.f;
      lsumB += (b0 + b1) + (b2 + b3);
      fp16x2 bl = __builtin_amdgcn_cvt_pkrtz(b0, b1);
      fp16x2 bh = __builtin_amdgcn_cvt_pkrtz(b2, b3);
      h16x4 PfB = (h16x4){(_Float16)bl.x, (_Float16)bl.y,
                          (_Float16)bh.x, (_Float16)bh.y};

      // O^T[f][i] += V^T[f][j] * P^T[j][i]   (V frags shared by both halves)
#pragma unroll
      for (int ft = 0; ft < 4; ++ft) {
        h16x4 Vf = *(const h16x4*)&Tc[(16 * ft + c) * 64 +
                                      (((4 * ct + qd) ^ c) << 2)];
        OA[ft] = __builtin_amdgcn_mfma_f32_16x16x16f16(Vf, PfA, OA[ft], 0, 0, 0);
        OB[ft] = __builtin_amdgcn_mfma_f32_16x16x16f16(Vf, PfB, OB[ft], 0, 0, 0);
      }
    }

    if (t < 7) {                                    // fill the other buffer
      _Float16* K2 = &Kb[(t & 1) ^ 1][0];
      _Float16* T2 = &Tb[(t & 1) ^ 1][0];
      *(uint4*)&K2[srow * 64 + ksw] = kr0;
      *(uint4*)&K2[(srow + 32) * 64 + ksw] = kr1;
      uint4 s0 = tswap ? (uint4){tr0.z, tr0.w, tr0.x, tr0.y} : tr0;
      uint4 s1 = tswap ? (uint4){tr1.z, tr1.w, tr1.x, tr1.y} : tr1;
      *(uint4*)&T2[srow * 64 + tsw] = s0;
      *(uint4*)&T2[(srow + 32) * 64 + tsw] = s1;
    }
    mA = mAn; mB = mBn;
  }

  // l: sum over qd groups (full 512-j quarter per row)
  lsumA += __shfl_xor(lsumA, 16, 64);
  lsumA += __shfl_xor(lsumA, 32, 64);
  lsumB += __shfl_xor(lsumB, 16, 64);
  lsumB += __shfl_xor(lsumB, 32, 64);

  const size_t sbase = (size_t)split * 16384 + bN;
  float* orowA = Opart + (sbase + i0 + c) * 64;
  float* orowB = Opart + (sbase + i0 + 16 + c) * 64;
#pragma unroll
  for (int ft = 0; ft < 4; ++ft) {
    *(f32x4*)(orowA + 16 * ft + 4 * qd) = OA[ft];
    *(f32x4*)(orowB + 16 * ft + 4 * qd) = OB[ft];
  }
  if (qd == 0) lpart[sbase + i0 + c] = lsumA;
  if (qd == 1) lpart[sbase + i0 + 16 + c] = lsumB;
}

// ---------------- phase 3: combine 8 splits + normalize + ELU ----------------
__global__ __launch_bounds__(256) void gat_combine(
    const float* __restrict__ Opart, const float* __restrict__ lpart,
    float* __restrict__ out)
{
  const int tid = threadIdx.x;
  const size_t row = (size_t)blockIdx.x * 16 + (tid >> 4);
  const int f4 = (tid & 15) * 4;
  const size_t R = 16384;
  float l = 0.f;
  f32x4 o = (f32x4){0.f, 0.f, 0.f, 0.f};
#pragma unroll
  for (int s = 0; s < 8; ++s) {
    l += lpart[s * R + row];
    o += *(const f32x4*)&Opart[(s * R + row) * 64 + f4];
  }
  float inv = 1.0f / l;
  float4 res;
  float v;
  v = o.x * inv; res.x = v > 0.f ? v : __expf(v) - 1.f;
  v = o.y * inv; res.y = v > 0.f ? v : __expf(v) - 1.f;
  v = o.z * inv; res.z = v > 0.f ? v : __expf(v) - 1.f;
  v = o.w * inv; res.w = v > 0.f ? v : __expf(v) - 1.f;
  *(float4*)&out[row * 64 + f4] = res;
}

extern "C" void kernel_launch(void* const* d_in, const int* in_sizes, int n_in,
                              void* d_out, int out_size, void* d_ws, size_t ws_size,
                              hipStream_t stream) {
  const float* x  = (const float*)d_in[0];
  const int* adj  = (const int*)d_in[1];
  const float* W  = (const float*)d_in[2];
  const float* a  = (const float*)d_in[3];
  float* out = (float*)d_out;

  char* ws = (char*)d_ws;
  _Float16* h16  = (_Float16*)(ws);                      // 2 MB
  _Float16* hT16 = (_Float16*)(ws + (2u << 20));         // 2 MB
  _Float16* q16  = (_Float16*)(ws + (4u << 20));         // 2 MB
  float* sS = (float*)(ws + (6u << 20));                 // 64 KB
  float* sN = (float*)(ws + (6u << 20) + (64u << 10));   // 64 KB
  float* Opart = (float*)(ws + (6u << 20) + (128u << 10));          // 33.6 MB
  float* lpart = (float*)(ws + (6u << 20) + (128u << 10) + (34u << 20)); // 512 KB
  unsigned long long* mask =
      (unsigned long long*)(ws + (6u << 20) + (128u << 10) + (35u << 20)); // 8.4 MB

  gat_mask<<<4096, 256, 0, stream>>>(adj, mask);
  gat_phase1<<<512, 256, 0, stream>>>(x, W, a, h16, hT16, q16, sS, sN);
  gat_phase2<<<1024, 256, 0, stream>>>(h16, hT16, q16, sS, sN, mask, Opart, lpart);
  gat_combine<<<1024, 256, 0, stream>>>(Opart, lpart, out);
}

// Round 7
// 394.469 us; speedup vs baseline: 1.2132x; 1.2132x over previous
//
#include <hip/hip_runtime.h>

// GAT as flash-attention, round 7 = R3 (best, 409us) + three targeted fixes:
//  - adj folded back into phase2 (268 MB stream overlaps compute; no mask pass)
//  - double-buffered XOR-swizzled LDS: 1 barrier/tile, conflict-free reads
//  - issue order: K/V staging (L2) before adj (HBM) so ds_write's vmcnt wait
//    doesn't drain the adj stream; sN staged to LDS once
//  - fixed-scale softmax (exp2, no running max); S^T MFMA formulation;
//    4-way j-split, 1024 blocks, 16-row waves (VGPR ~100, no spills)

typedef __attribute__((ext_vector_type(4))) float f32x4;
typedef __attribute__((ext_vector_type(4))) _Float16 h16x4;
typedef __attribute__((ext_vector_type(8))) _Float16 h16x8;
typedef __attribute__((ext_vector_type(2))) __fp16 fp16x2;

#define L2E 1.4426950408889634f

// ---------------- phase 1: h = x@W (fp32), scaled biases, fp16 packs --------
__global__ __launch_bounds__(256) void gat_phase1(
    const float* __restrict__ x,        // [4][4096][128]
    const float* __restrict__ W,        // [128][64]
    const float* __restrict__ a,        // [192]
    _Float16* __restrict__ h16,         // [4][4096][64]
    _Float16* __restrict__ hT16,        // [4][64][4096]
    _Float16* __restrict__ q16,         // [4][4096][64]  (pre-scaled by log2e)
    float* __restrict__ sS,             // [4][4096]      (pre-scaled by log2e)
    float* __restrict__ sN)             // [4][4096]      (pre-scaled by log2e)
{
  __shared__ float xs[32 * 132];        // x tile [row][k], stride 132
  __shared__ float ws[128 * 64];        // W natural [k][f] (broadcast/2-way)
  const int tid = threadIdx.x;
  const int bx  = blockIdx.x;
  const int b   = bx >> 7;
  const int n0  = (bx & 127) << 5;
  const float* xb = x + ((size_t)b * 4096 + n0) * 128;

#pragma unroll
  for (int p = 0; p < 4; ++p) {
    int idx = tid + p * 256;
    int row = idx >> 5, c4 = idx & 31;
    float4 v = ((const float4*)(xb + row * 128))[c4];
    *(float4*)&xs[row * 132 + c4 * 4] = v;
  }
#pragma unroll
  for (int p = 0; p < 8; ++p) {
    int idx = tid + p * 256;
    ((float4*)ws)[idx] = ((const float4*)W)[idx];
  }
  __syncthreads();

  const int tx = tid & 15;   // f = 4*tx + fi
  const int ty = tid >> 4;   // n = n0 + 2*ty + ri
  f32x4 acc0 = (f32x4){0.f, 0.f, 0.f, 0.f};
  f32x4 acc1 = (f32x4){0.f, 0.f, 0.f, 0.f};

#pragma unroll 8
  for (int k = 0; k < 128; k += 4) {
    f32x4 x0 = *(const f32x4*)&xs[(2 * ty) * 132 + k];
    f32x4 x1 = *(const f32x4*)&xs[(2 * ty + 1) * 132 + k];
    f32x4 w0 = *(const f32x4*)&ws[(k + 0) * 64 + 4 * tx];
    f32x4 w1 = *(const f32x4*)&ws[(k + 1) * 64 + 4 * tx];
    f32x4 w2 = *(const f32x4*)&ws[(k + 2) * 64 + 4 * tx];
    f32x4 w3 = *(const f32x4*)&ws[(k + 3) * 64 + 4 * tx];
    acc0 += x0.x * w0 + x0.y * w1 + x0.z * w2 + x0.w * w3;
    acc1 += x1.x * w0 + x1.y * w1 + x1.z * w2 + x1.w * w3;
  }
  float acc[2][4] = {{acc0.x, acc0.y, acc0.z, acc0.w},
                     {acc1.x, acc1.y, acc1.z, acc1.w}};

  float a1r[4], a2r[4], a3r[4];
#pragma unroll
  for (int f = 0; f < 4; ++f) {
    a1r[f] = a[4 * tx + f] * L2E;
    a2r[f] = a[64 + 4 * tx + f] * L2E;
    a3r[f] = a[128 + 4 * tx + f] * L2E;
  }
  const size_t bN = (size_t)b * 4096;
#pragma unroll
  for (int r = 0; r < 2; ++r) {
    float p1 = 0.f, p2 = 0.f;
#pragma unroll
    for (int f = 0; f < 4; ++f) { p1 += acc[r][f] * a1r[f]; p2 += acc[r][f] * a2r[f]; }
#pragma unroll
    for (int m = 1; m < 16; m <<= 1) {
      p1 += __shfl_xor(p1, m, 64);
      p2 += __shfl_xor(p2, m, 64);
    }
    if (tx == 0) {
      int n = n0 + 2 * ty + r;
      sS[bN + n] = p1;
      sN[bN + n] = p2;
    }
  }
#pragma unroll
  for (int r = 0; r < 2; ++r) {
    int n = n0 + 2 * ty + r;
    h16x4 hv, qv;
#pragma unroll
    for (int f = 0; f < 4; ++f) {
      hv[f] = (_Float16)acc[r][f];
      qv[f] = (_Float16)(acc[r][f] * a3r[f]);
    }
    *(h16x4*)&h16[(bN + n) * 64 + 4 * tx] = hv;
    *(h16x4*)&q16[(bN + n) * 64 + 4 * tx] = qv;
  }
  __syncthreads();                       // xs reads done; reuse as hT staging
  _Float16* hTs = (_Float16*)xs;         // [64][40] halves
#pragma unroll
  for (int f = 0; f < 4; ++f)
#pragma unroll
    for (int r = 0; r < 2; ++r)
      hTs[(4 * tx + f) * 40 + 2 * ty + r] = (_Float16)acc[r][f];
  __syncthreads();
  {
    int f = tid >> 2, part = tid & 3;
    uint4 v = *(uint4*)&hTs[f * 40 + 8 * part];
    *(uint4*)&hT16[((size_t)b * 64 + f) * 4096 + n0 + 8 * part] = v;
  }
}

// ---------------- phase 2: masked softmax-attention partials ----------------
// 1024 blocks (b(4), split(4), itile(64)) x 256 thr (4 waves x 16 rows).
// j-quarter = 1024 = 16 tiles of 64. Double-buffered XOR-swizzled LDS,
// 1 barrier/tile. adj read directly (uint4, 16 rows x 64 B per inst).
// MFMA layouts: 16x16x32 A[m=lane&15][k=qd*8+j], B[k=qd*8+j][n=lane&15],
//               16x16x16 A[m=lane&15][k=qd*4+r], B[k=qd*4+r][n=lane&15],
//               C/D row=4*qd+reg, col=lane&15.
__global__ __launch_bounds__(256, 4) void gat_phase2(
    const _Float16* __restrict__ h16,
    const _Float16* __restrict__ hT16,
    const _Float16* __restrict__ q16,
    const float* __restrict__ sS,
    const float* __restrict__ sN,
    const int* __restrict__ adj,
    float* __restrict__ Opart,          // [4][16384][64]
    float* __restrict__ lpart)          // [4][16384]
{
  __shared__ _Float16 Kb[2][4096];   // K tile [j][f], stride 64, chunk^(j&7)
  __shared__ _Float16 Tb[2][4096];   // V^T tile [f][j], stride 64, 8B-chunk^f
  __shared__ float sNl[1024];

  const int tid = threadIdx.x;
  const int w = tid >> 6, lane = tid & 63;
  const int qd = lane >> 4, c = lane & 15;
  const int bx = blockIdx.x;
  const int b = bx & 3;
  const int split = (bx >> 2) & 3;
  const int it = bx >> 4;
  const int i0 = it * 64 + w * 16;
  const int jq0 = split * 1024;
  const size_t bN = (size_t)b * 4096;

  // Q fragment (B-op of S^T): lane holds Q[i=i0+c][f-slice]
  const _Float16* qrow = q16 + (bN + i0 + c) * 64;
  h16x8 Qf0 = *(const h16x8*)(qrow + qd * 8);
  h16x8 Qf1 = *(const h16x8*)(qrow + 32 + qd * 8);
  const float ss = sS[bN + i0 + c];

  const int* abase = adj + (bN + i0 + c) * 4096 + jq0 + 4 * qd;

  // staging addressing: thread -> rows srow, srow+32; 16B chunk (swizzled)
  const int srow = tid >> 3, chunk = tid & 7;
  const int ksw = (chunk ^ (srow & 7)) << 3;
  const int tsw = (chunk ^ ((srow >> 1) & 7)) << 3;
  const bool tswap = (srow & 1);
  const _Float16* hsrc = h16 + (bN + jq0 + srow) * 64 + chunk * 8;
  const _Float16* tsrc = hT16 + ((size_t)b * 64 + srow) * 4096 + jq0 + chunk * 8;

  f32x4 O[4];
#pragma unroll
  for (int ft = 0; ft < 4; ++ft) O[ft] = (f32x4){0.f, 0.f, 0.f, 0.f};
  float lsum = 0.f;

  // stage tile 0 into buffer 0, sN into LDS, adj tile 0 into regs
  {
    uint4 k0 = *(const uint4*)hsrc, k1 = *(const uint4*)(hsrc + 32 * 64);
    uint4 t0 = *(const uint4*)tsrc, t1 = *(const uint4*)(tsrc + 32 * 4096);
    *(uint4*)&Kb[0][srow * 64 + ksw] = k0;
    *(uint4*)&Kb[0][(srow + 32) * 64 + ksw] = k1;
    uint4 s0 = tswap ? (uint4){t0.z, t0.w, t0.x, t0.y} : t0;
    uint4 s1 = tswap ? (uint4){t1.z, t1.w, t1.x, t1.y} : t1;
    *(uint4*)&Tb[0][srow * 64 + tsw] = s0;
    *(uint4*)&Tb[0][(srow + 32) * 64 + tsw] = s1;
  }
  ((f32x4*)sNl)[tid] = *(const f32x4*)(sN + bN + jq0 + 4 * tid);
  uint4 av[4];
#pragma unroll
  for (int ct = 0; ct < 4; ++ct) av[ct] = *(const uint4*)(abase + 16 * ct);

  for (int t = 0; t < 16; ++t) {
    __syncthreads();                                // buf[t&1] (+sNl) visible

    uint4 kr0, kr1, tr0, tr1;
    uint4 avn[4] = {av[0], av[1], av[2], av[3]};
    if (t < 15) {
      // K/V staging loads FIRST (L2-hot, coalesced)...
      const _Float16* hs = hsrc + (t + 1) * 4096;
      const _Float16* ts = tsrc + (t + 1) * 64;
      kr0 = *(const uint4*)hs; kr1 = *(const uint4*)(hs + 32 * 64);
      tr0 = *(const uint4*)ts; tr1 = *(const uint4*)(ts + 32 * 4096);
      // ...then adj (HBM) so the ds_write vmcnt wait doesn't drain it
#pragma unroll
      for (int ct = 0; ct < 4; ++ct)
        avn[ct] = *(const uint4*)(abase + (t + 1) * 64 + 16 * ct);
    }

    const _Float16* Kc = &Kb[t & 1][0];
    const _Float16* Tc = &Tb[t & 1][0];
#pragma unroll
    for (int ct = 0; ct < 4; ++ct) {
      const int krow = 16 * ct + c;
      h16x8 Kf0 = *(const h16x8*)&Kc[krow * 64 + ((qd ^ (c & 7)) << 3)];
      h16x8 Kf1 = *(const h16x8*)&Kc[krow * 64 + (((qd + 4) ^ (c & 7)) << 3)];
      f32x4 Sv = (f32x4){0.f, 0.f, 0.f, 0.f};
      Sv = __builtin_amdgcn_mfma_f32_16x16x32_f16(Kf0, Qf0, Sv, 0, 0, 0);
      Sv = __builtin_amdgcn_mfma_f32_16x16x32_f16(Kf1, Qf1, Sv, 0, 0, 0);

      f32x4 snv = ((const f32x4*)sNl)[t * 16 + 4 * ct + qd];   // broadcast
      f32x4 ev = Sv + snv + ss;                     // e * log2e
      f32x4 tv = __builtin_elementwise_max(ev, ev * 0.2f);  // leakyrelu
      float p0 = __builtin_amdgcn_exp2f(tv.x);
      float p1 = __builtin_amdgcn_exp2f(tv.y);
      float p2 = __builtin_amdgcn_exp2f(tv.z);
      float p3 = __builtin_amdgcn_exp2f(tv.w);
      p0 = av[ct].x ? p0 : 0.f;
      p1 = av[ct].y ? p1 : 0.f;
      p2 = av[ct].z ? p2 : 0.f;
      p3 = av[ct].w ? p3 : 0.f;
      lsum += (p0 + p1) + (p2 + p3);
      fp16x2 plo = __builtin_amdgcn_cvt_pkrtz(p0, p1);
      fp16x2 phi = __builtin_amdgcn_cvt_pkrtz(p2, p3);
      h16x4 Pf = (h16x4){(_Float16)plo.x, (_Float16)plo.y,
                         (_Float16)phi.x, (_Float16)phi.y};  // P^T[j][i=c]

      // O^T[f][i] += V^T[f][j] * P^T[j][i]
#pragma unroll
      for (int ft = 0; ft < 4; ++ft) {
        h16x4 Vf = *(const h16x4*)&Tc[(16 * ft + c) * 64 +
                                      (((4 * ct + qd) ^ c) << 2)];
        O[ft] = __builtin_amdgcn_mfma_f32_16x16x16f16(Vf, Pf, O[ft], 0, 0, 0);
      }
    }

    if (t < 15) {                                   // fill the other buffer
      _Float16* K2 = &Kb[(t & 1) ^ 1][0];
      _Float16* T2 = &Tb[(t & 1) ^ 1][0];
      *(uint4*)&K2[srow * 64 + ksw] = kr0;
      *(uint4*)&K2[(srow + 32) * 64 + ksw] = kr1;
      uint4 s0 = tswap ? (uint4){tr0.z, tr0.w, tr0.x, tr0.y} : tr0;
      uint4 s1 = tswap ? (uint4){tr1.z, tr1.w, tr1.x, tr1.y} : tr1;
      *(uint4*)&T2[srow * 64 + tsw] = s0;
      *(uint4*)&T2[(srow + 32) * 64 + tsw] = s1;
    }
#pragma unroll
    for (int ct = 0; ct < 4; ++ct) av[ct] = avn[ct];
  }

  // l: sum over qd groups (full j-quarter per row i=i0+c)
  lsum += __shfl_xor(lsum, 16, 64);
  lsum += __shfl_xor(lsum, 32, 64);

  float* orow = Opart + ((size_t)split * 16384 + bN + i0 + c) * 64;
#pragma unroll
  for (int ft = 0; ft < 4; ++ft)
    *(f32x4*)(orow + 16 * ft + 4 * qd) = O[ft];
  if (lane < 16) lpart[split * 16384 + bN + i0 + c] = lsum;
}

// ---------------- phase 3: combine splits + normalize + ELU ----------------
__global__ __launch_bounds__(256) void gat_combine(
    const float* __restrict__ Opart, const float* __restrict__ lpart,
    float* __restrict__ out)
{
  const int tid = threadIdx.x;
  const size_t row = (size_t)blockIdx.x * 16 + (tid >> 4);
  const int f4 = (tid & 15) * 4;
  const size_t R = 16384;
  float l = lpart[row] + lpart[R + row] + lpart[2 * R + row] + lpart[3 * R + row];
  f32x4 o = *(const f32x4*)&Opart[row * 64 + f4];
  o += *(const f32x4*)&Opart[(R + row) * 64 + f4];
  o += *(const f32x4*)&Opart[(2 * R + row) * 64 + f4];
  o += *(const f32x4*)&Opart[(3 * R + row) * 64 + f4];
  float inv = 1.0f / l;
  float4 res;
  float v;
  v = o.x * inv; res.x = v > 0.f ? v : __expf(v) - 1.f;
  v = o.y * inv; res.y = v > 0.f ? v : __expf(v) - 1.f;
  v = o.z * inv; res.z = v > 0.f ? v : __expf(v) - 1.f;
  v = o.w * inv; res.w = v > 0.f ? v : __expf(v) - 1.f;
  *(float4*)&out[row * 64 + f4] = res;
}

extern "C" void kernel_launch(void* const* d_in, const int* in_sizes, int n_in,
                              void* d_out, int out_size, void* d_ws, size_t ws_size,
                              hipStream_t stream) {
  const float* x  = (const float*)d_in[0];
  const int* adj  = (const int*)d_in[1];
  const float* W  = (const float*)d_in[2];
  const float* a  = (const float*)d_in[3];
  float* out = (float*)d_out;

  char* ws = (char*)d_ws;
  _Float16* h16  = (_Float16*)(ws);                      // 2 MB
  _Float16* hT16 = (_Float16*)(ws + (2u << 20));         // 2 MB
  _Float16* q16  = (_Float16*)(ws + (4u << 20));         // 2 MB
  float* sS = (float*)(ws + (6u << 20));                 // 64 KB
  float* sN = (float*)(ws + (6u << 20) + (64u << 10));   // 64 KB
  float* Opart = (float*)(ws + (6u << 20) + (128u << 10));               // 16.8 MB
  float* lpart = (float*)(ws + (6u << 20) + (128u << 10) + (17u << 20)); // 256 KB

  gat_phase1<<<512, 256, 0, stream>>>(x, W, a, h16, hT16, q16, sS, sN);
  gat_phase2<<<1024, 256, 0, stream>>>(h16, hT16, q16, sS, sN, adj, Opart, lpart);
  gat_combine<<<1024, 256, 0, stream>>>(Opart, lpart, out);
}